// Round 1
// baseline (325.190 us; speedup 1.0000x reference)
//
#include <hip/hip_runtime.h>

// Problem constants
#define U_CNT 784   // H*W = 28*28 (both u and v extents)
#define DKH   128   // key/value head dim
#define DD    512   // input channel dim
#define NQ    8     // query batch
#define NS    16    // support classes

typedef short bf16x8 __attribute__((ext_vector_type(8)));
typedef float f32x4  __attribute__((ext_vector_type(4)));

__device__ __forceinline__ unsigned short f2bf(float f) {
  unsigned u = __builtin_bit_cast(unsigned, f);
  u += 0x7fffu + ((u >> 16) & 1u);   // round-to-nearest-even
  return (unsigned short)(u >> 16);
}

// ---------------------------------------------------------------- K0: cast W
// Wkv_bf16[256][512] = concat(Wk, Wv) rounded to bf16
__global__ void cast_w(const float* __restrict__ Wk, const float* __restrict__ Wv,
                       unsigned short* __restrict__ Wkv) {
  int base = (blockIdx.x * 256 + threadIdx.x) * 8;
#pragma unroll
  for (int i = 0; i < 8; ++i) {
    int e = base + i;
    int ko = e >> 9, d = e & 511;
    float v = (ko < 128) ? Wk[ko * 512 + d] : Wv[(ko - 128) * 512 + d];
    Wkv[e] = f2bf(v);
  }
}

// ------------------------------------------------------------- K1: projection
// Per image m (0..7 query, 8..23 support): Y = Wkv @ X  (256 x 784), K=512.
// Stores transposed, k-contiguous:
//   rows 0..127  -> q_t[b][u][k] (bf16, x 1/sqrt(128)) or sk_t[n][v][k] (bf16)
//   rows 128..255-> qv_t[b][u][k] or sv_t[n][v][k] (fp32)
__global__ __launch_bounds__(256, 2)
void proj_kernel(const float* __restrict__ query, const float* __restrict__ support,
                 const unsigned short* __restrict__ Wkv,
                 unsigned short* __restrict__ q_t, unsigned short* __restrict__ sk_t,
                 float* __restrict__ qv_t, float* __restrict__ sv_t) {
  int m = blockIdx.y;
  int wave = threadIdx.x >> 6;
  int p0 = blockIdx.x * 64 + wave * 16;
  if (p0 >= U_CNT) return;                 // ragged last tile (wave-uniform)
  int l = threadIdx.x & 63;
  int col = l & 15, row = l >> 4;
  int p = p0 + col;
  const float* X = (m < 8) ? (query + (size_t)m * DD * U_CNT)
                           : (support + (size_t)(m - 8) * DD * U_CNT);
  f32x4 acc[16];
  f32x4 zero = {0.f, 0.f, 0.f, 0.f};
#pragma unroll
  for (int r = 0; r < 16; ++r) acc[r] = zero;

  for (int ds = 0; ds < 16; ++ds) {
    int d0 = ds * 32 + row * 8;
    // B fragment: B[k=d][n=p] = X[d][p], cast fp32->bf16
    bf16x8 bfrag;
#pragma unroll
    for (int j = 0; j < 8; ++j) {
      float x = X[(size_t)(d0 + j) * U_CNT + p];
      bfrag[j] = (short)f2bf(x);
    }
    // A fragments: A[m=k_out][k=d] = Wkv[k_out][d]  (16B contiguous per lane)
#pragma unroll
    for (int r = 0; r < 16; ++r) {
      const bf16x8* ap = (const bf16x8*)(Wkv + (size_t)(r * 16 + col) * DD + d0);
      acc[r] = __builtin_amdgcn_mfma_f32_16x16x32_bf16(*ap, bfrag, acc[r], 0, 0, 0);
    }
  }

  int img = (m < 8) ? m : m - 8;
#pragma unroll
  for (int r = 0; r < 16; ++r) {
    int kb = r * 16 + row * 4;   // D rows: k_out = r*16 + row*4 + j ; cols: p
    if (r < 8) {
      float sc = (m < 8) ? 0.08838834764831845f : 1.0f;  // fold 1/sqrt(128) into q
      ushort4 o;
      o.x = f2bf(acc[r][0] * sc); o.y = f2bf(acc[r][1] * sc);
      o.z = f2bf(acc[r][2] * sc); o.w = f2bf(acc[r][3] * sc);
      unsigned short* dst = (m < 8) ? q_t : sk_t;
      *(ushort4*)(dst + (size_t)(img * U_CNT + p) * DKH + kb) = o;
    } else {
      float4 o = make_float4(acc[r][0], acc[r][1], acc[r][2], acc[r][3]);
      float* dst = (m < 8) ? qv_t : sv_t;
      *(float4*)(dst + (size_t)(img * U_CNT + p) * DKH + (kb - 128)) = o;
    }
  }
}

// ------------------------------------------------- K2: qv reductions (S1, S2)
// S1[b] = sum_{u,k} qv^2 ;  S2[b][k] = sum_u qv[b][u][k]
__global__ __launch_bounds__(256)
void qv_reduce(const float* __restrict__ qv_t, float* __restrict__ S1,
               float* __restrict__ S2) {
  int b = blockIdx.y, chunk = blockIdx.x;
  int t = threadIdx.x;
  int k = t & 127, half = t >> 7;
  float ssq = 0.f, ssum = 0.f;
  for (int i = 0; i < 56; ++i) {
    int u = chunk * 112 + i * 2 + half;
    float v = qv_t[(size_t)(b * U_CNT + u) * DKH + k];
    ssq += v * v; ssum += v;
  }
  __shared__ float red[256];
  __shared__ float sw[4];
  red[t] = ssum;
  __syncthreads();
  if (t < 128) atomicAdd(&S2[b * DKH + k], red[t] + red[t + 128]);
  float s = ssq;
#pragma unroll
  for (int o = 32; o >= 1; o >>= 1) s += __shfl_xor(s, o, 64);
  if ((t & 63) == 0) sw[t >> 6] = s;
  __syncthreads();
  if (t == 0) atomicAdd(&S1[b], sw[0] + sw[1] + sw[2] + sw[3]);
}

// -------------------------------------------- K3: scores + softmax_n + sum_u
// Per wave: (b, v-tile16, u-chunk of 7 u-tiles). 16 n-accumulators so softmax
// over n is pure per-lane register math. Writes w_part[uc][b][n][v].
__global__ __launch_bounds__(256, 2)
void score_kernel(const unsigned short* __restrict__ q_t,
                  const unsigned short* __restrict__ sk_t,
                  float* __restrict__ w_part) {
  int gw = blockIdx.x * 4 + (threadIdx.x >> 6);
  int uc = gw % 7;
  int vt = (gw / 7) % 49;
  int b  = gw / 343;
  int l = threadIdx.x & 63;
  int col = l & 15, row = l >> 4;
  int v = vt * 16 + col;

  float w_acc[16];
#pragma unroll
  for (int n = 0; n < NS; ++n) w_acc[n] = 0.f;
  f32x4 zero = {0.f, 0.f, 0.f, 0.f};

  for (int i = 0; i < 7; ++i) {
    int ut = uc * 7 + i;
    // A fragments (held in regs for all 4 k-steps): A[m=u][k]
    const unsigned short* ab =
        q_t + (size_t)(b * U_CNT + ut * 16 + col) * DKH + row * 8;
    bf16x8 A0 = *(const bf16x8*)(ab);
    bf16x8 A1 = *(const bf16x8*)(ab + 32);
    bf16x8 A2 = *(const bf16x8*)(ab + 64);
    bf16x8 A3 = *(const bf16x8*)(ab + 96);

    f32x4 acc[16];
#pragma unroll
    for (int n = 0; n < NS; ++n) acc[n] = zero;
#pragma unroll
    for (int n = 0; n < NS; ++n) {
      const unsigned short* bp =
          sk_t + ((size_t)n * U_CNT + v) * DKH + row * 8;
      acc[n] = __builtin_amdgcn_mfma_f32_16x16x32_bf16(A0, *(const bf16x8*)(bp),      acc[n], 0, 0, 0);
      acc[n] = __builtin_amdgcn_mfma_f32_16x16x32_bf16(A1, *(const bf16x8*)(bp + 32), acc[n], 0, 0, 0);
      acc[n] = __builtin_amdgcn_mfma_f32_16x16x32_bf16(A2, *(const bf16x8*)(bp + 64), acc[n], 0, 0, 0);
      acc[n] = __builtin_amdgcn_mfma_f32_16x16x32_bf16(A3, *(const bf16x8*)(bp + 96), acc[n], 0, 0, 0);
    }
    // softmax over n per (u,v); scores ~ N(0,1) -> no max subtraction needed
#pragma unroll
    for (int j = 0; j < 4; ++j) {
      float e[16]; float dsum = 0.f;
#pragma unroll
      for (int n = 0; n < NS; ++n) { e[n] = __expf(acc[n][j]); dsum += e[n]; }
      float rr = __builtin_amdgcn_rcpf(dsum);
#pragma unroll
      for (int n = 0; n < NS; ++n) w_acc[n] += e[n] * rr;
    }
  }
  // combine the 4 row-groups holding the same v (=l&15)
#pragma unroll
  for (int n = 0; n < NS; ++n) {
    w_acc[n] += __shfl_xor(w_acc[n], 16, 64);
    w_acc[n] += __shfl_xor(w_acc[n], 32, 64);
  }
  if (l < 16) {
    int vv = vt * 16 + l;
#pragma unroll
    for (int n = 0; n < NS; ++n)
      w_part[((size_t)(uc * 8 + b) * 16 + n) * U_CNT + vv] = w_acc[n];
  }
}

// --------------------------- K4: a = sum_n w*sv, reduced on the fly (T1, T2)
__global__ __launch_bounds__(256)
void align_kernel(const float* __restrict__ w_part, const float* __restrict__ sv_t,
                  float* __restrict__ T1, float* __restrict__ T2) {
  int vt = blockIdx.x, b = blockIdx.y;
  int t = threadIdx.x;
  __shared__ float w_sh[16][16];   // [v_local][n]
  __shared__ float red[256];
  __shared__ float sw[4];
  {
    int n = t & 15, vl = t >> 4;
    float s = 0.f;
#pragma unroll
    for (int uc = 0; uc < 7; ++uc)
      s += w_part[((size_t)(uc * 8 + b) * 16 + n) * U_CNT + vt * 16 + vl];
    w_sh[vl][n] = s;
  }
  __syncthreads();
  int k = t & 127, vo = t >> 7;
  float t1 = 0.f, t2 = 0.f;
  for (int vi = vo; vi < 16; vi += 2) {
    int v = vt * 16 + vi;
    float a = 0.f;
#pragma unroll
    for (int n = 0; n < NS; ++n)
      a += w_sh[vi][n] * sv_t[((size_t)n * U_CNT + v) * DKH + k];
    t1 += a * a; t2 += a;
  }
  red[t] = t2;
  __syncthreads();
  if (t < 128) atomicAdd(&T2[b * DKH + k], red[t] + red[t + 128]);
  float s = t1;
#pragma unroll
  for (int o = 32; o >= 1; o >>= 1) s += __shfl_xor(s, o, 64);
  if ((t & 63) == 0) sw[t >> 6] = s;
  __syncthreads();
  if (t == 0) atomicAdd(&T1[b], sw[0] + sw[1] + sw[2] + sw[3]);
}

// ----------------------------------------------------------------- K5: final
__global__ void final_kernel(const float* __restrict__ S1, const float* __restrict__ S2,
                             const float* __restrict__ T1, const float* __restrict__ T2,
                             float* __restrict__ out) {
  int b = blockIdx.x, t = threadIdx.x;  // 128 threads
  float p = S2[b * DKH + t] * T2[b * DKH + t];
#pragma unroll
  for (int o = 32; o >= 1; o >>= 1) p += __shfl_xor(p, o, 64);
  __shared__ float s2[2];
  if ((t & 63) == 0) s2[t >> 6] = p;
  __syncthreads();
  if (t == 0) {
    float cross = s2[0] + s2[1];
    out[b] = (784.0f * (T1[b] + S1[b]) - 2.0f * cross) * (1.0f / (784.0f * 784.0f));
  }
}

// ----------------------------------------------------------------- launcher
extern "C" void kernel_launch(void* const* d_in, const int* in_sizes, int n_in,
                              void* d_out, int out_size, void* d_ws, size_t ws_size,
                              hipStream_t stream) {
  const float* query   = (const float*)d_in[0];
  const float* support = (const float*)d_in[1];
  const float* Wk      = (const float*)d_in[2];
  const float* Wv      = (const float*)d_in[3];
  float* out = (float*)d_out;
  char* ws = (char*)d_ws;

  // workspace layout (all offsets 256B-aligned)
  unsigned short* Wkv  = (unsigned short*)(ws + 0);         //   256KB
  unsigned short* q_t  = (unsigned short*)(ws + 262144);    //  1.53MB bf16 [8][784][128]
  unsigned short* sk_t = (unsigned short*)(ws + 1867776);   //  3.06MB bf16 [16][784][128]
  float*          qv_t = (float*)(ws + 5079040);            //  3.06MB f32  [8][784][128]
  float*          sv_t = (float*)(ws + 8290304);            //  6.13MB f32  [16][784][128]
  float*          w_part = (float*)(ws + 14712832);         //  2.68MB f32  [7][8][16][784]
  float*          S1 = (float*)(ws + 17522688);             // 8
  float*          T1 = (float*)(ws + 17522688 + 32);        // 8
  float*          S2 = (float*)(ws + 17522688 + 64);        // 8x128
  float*          T2 = (float*)(ws + 17522688 + 64 + 4096); // 8x128
  if (ws_size < (size_t)17531000) return;

  hipMemsetAsync(ws + 17522688, 0, 64 + 8192, stream);
  cast_w<<<64, 256, 0, stream>>>(Wk, Wv, Wkv);
  proj_kernel<<<dim3(13, 24), 256, 0, stream>>>(query, support, Wkv, q_t, sk_t, qv_t, sv_t);
  qv_reduce<<<dim3(7, 8), 256, 0, stream>>>(qv_t, S1, S2);
  score_kernel<<<686, 256, 0, stream>>>(q_t, sk_t, w_part);
  align_kernel<<<dim3(49, 8), 256, 0, stream>>>(w_part, sv_t, T1, T2);
  final_kernel<<<8, 128, 0, stream>>>(S1, S2, T1, T2, out);
}

// Round 2
// 289.961 us; speedup vs baseline: 1.1215x; 1.1215x over previous
//
#include <hip/hip_runtime.h>

// Problem constants
#define U_CNT 784   // H*W = 28*28 (both u and v extents)
#define DKH   128   // key/value head dim
#define DD    512   // input channel dim
#define NS    16    // support classes

typedef short bf16x8 __attribute__((ext_vector_type(8)));
typedef float f32x4  __attribute__((ext_vector_type(4)));

__device__ __forceinline__ unsigned short f2bf(float f) {
  unsigned u = __builtin_bit_cast(unsigned, f);
  u += 0x7fffu + ((u >> 16) & 1u);   // round-to-nearest-even
  return (unsigned short)(u >> 16);
}

// ---------------------------------------------------------------- K0: cast W
__global__ void cast_w(const float* __restrict__ Wk, const float* __restrict__ Wv,
                       unsigned short* __restrict__ Wkv) {
  int base = (blockIdx.x * 256 + threadIdx.x) * 8;
#pragma unroll
  for (int i = 0; i < 8; ++i) {
    int e = base + i;
    int ko = e >> 9, d = e & 511;
    float v = (ko < 128) ? Wk[ko * 512 + d] : Wv[(ko - 128) * 512 + d];
    Wkv[e] = f2bf(v);
  }
}

// ------------------------------------------------------------- K1: projection
// Per image m: Y = Wkv @ X (256 x 784), K=512.
//  m<8  (query):  rows 0..127 -> q_t[b][u][k] bf16 (x 1/sqrt(128));
//                 rows 128..255 (qv) reduced inline into S1[b], S2[b][k].
//  m>=8 (support):rows 0..127 -> sk_t[n][v][k] bf16; rows 128..255 -> sv_t f32.
__global__ __launch_bounds__(256, 2)
void proj_kernel(const float* __restrict__ query, const float* __restrict__ support,
                 const unsigned short* __restrict__ Wkv,
                 unsigned short* __restrict__ q_t, unsigned short* __restrict__ sk_t,
                 float* __restrict__ sv_t, float* __restrict__ S1, float* __restrict__ S2) {
  int m = blockIdx.y;
  int wave = threadIdx.x >> 6;
  int p0 = blockIdx.x * 64 + wave * 16;
  if (p0 >= U_CNT) return;                 // ragged last tile (wave-uniform)
  int l = threadIdx.x & 63;
  int col = l & 15, rowg = l >> 4;
  int p = p0 + col;
  const float* X = (m < 8) ? (query + (size_t)m * DD * U_CNT)
                           : (support + (size_t)(m - 8) * DD * U_CNT);
  f32x4 acc[16];
  f32x4 zero = {0.f, 0.f, 0.f, 0.f};
#pragma unroll
  for (int r = 0; r < 16; ++r) acc[r] = zero;

  for (int ds = 0; ds < 16; ++ds) {
    int d0 = ds * 32 + rowg * 8;
    bf16x8 bfrag;
#pragma unroll
    for (int j = 0; j < 8; ++j) {
      float x = X[(size_t)(d0 + j) * U_CNT + p];
      bfrag[j] = (short)f2bf(x);
    }
#pragma unroll
    for (int r = 0; r < 16; ++r) {
      const bf16x8* ap = (const bf16x8*)(Wkv + (size_t)(r * 16 + col) * DD + d0);
      acc[r] = __builtin_amdgcn_mfma_f32_16x16x32_bf16(*ap, bfrag, acc[r], 0, 0, 0);
    }
  }

  if (m < 8) {
    // rows 0..7 -> q_t (scaled bf16)
#pragma unroll
    for (int r = 0; r < 8; ++r) {
      int kb = r * 16 + rowg * 4;
      const float sc = 0.08838834764831845f;  // 1/sqrt(128)
      ushort4 o;
      o.x = f2bf(acc[r][0] * sc); o.y = f2bf(acc[r][1] * sc);
      o.z = f2bf(acc[r][2] * sc); o.w = f2bf(acc[r][3] * sc);
      *(ushort4*)(q_t + (size_t)(m * U_CNT + p) * DKH + kb) = o;
    }
    // rows 8..15 (qv) -> inline reductions
    float s1 = 0.f;
#pragma unroll
    for (int r = 8; r < 16; ++r) {
#pragma unroll
      for (int j = 0; j < 4; ++j) {
        float x = acc[r][j];
        s1 += x * x;
        x += __shfl_xor(x, 1, 64); x += __shfl_xor(x, 2, 64);
        x += __shfl_xor(x, 4, 64); x += __shfl_xor(x, 8, 64);
        if (col == 0) atomicAdd(&S2[m * DKH + (r - 8) * 16 + rowg * 4 + j], x);
      }
    }
#pragma unroll
    for (int o = 32; o >= 1; o >>= 1) s1 += __shfl_xor(s1, o, 64);
    if (l == 0) atomicAdd(&S1[m], s1);
  } else {
    int img = m - 8;
#pragma unroll
    for (int r = 0; r < 16; ++r) {
      int kb = r * 16 + rowg * 4;
      if (r < 8) {
        ushort4 o;
        o.x = f2bf(acc[r][0]); o.y = f2bf(acc[r][1]);
        o.z = f2bf(acc[r][2]); o.w = f2bf(acc[r][3]);
        *(ushort4*)(sk_t + (size_t)(img * U_CNT + p) * DKH + kb) = o;
      } else {
        float4 o = make_float4(acc[r][0], acc[r][1], acc[r][2], acc[r][3]);
        *(float4*)(sv_t + (size_t)(img * U_CNT + p) * DKH + (kb - 128)) = o;
      }
    }
  }
}

// -------------------------------------------- K3: scores + softmax_n + sum_u
// MFMA m-dim = class (16 = all of NS -> softmax needs one accumulator),
// n-dim = u. Per wave: 4 v's (sk frags register-resident), stream q u-tiles.
// Block = 4 waves sharing (b, uc), 16 consecutive v. Writes w_part[uc][b][v][n]
// as one contiguous 1KB block.
__global__ __launch_bounds__(256, 3)
void score_kernel(const unsigned short* __restrict__ q_t,
                  const unsigned short* __restrict__ sk_t,
                  float* __restrict__ w_part) {
  int bx = blockIdx.x;            // 1568 = 49 vb * 4 uc * 8 b
  int vb = bx % 49;
  int uc = (bx / 49) & 3;
  int b  = bx / 196;
  int wv = threadIdx.x >> 6;
  int l  = threadIdx.x & 63;
  int col = l & 15, rowg = l >> 4;
  int vbase = vb * 16 + wv * 4;

  // A frags: A[m=class=col][k], for 4 v x 4 k-steps (64 VGPRs, resident)
  bf16x8 A[4][4];
#pragma unroll
  for (int v = 0; v < 4; ++v) {
    const unsigned short* ap =
        sk_t + ((size_t)col * U_CNT + vbase + v) * DKH + rowg * 8;
#pragma unroll
    for (int s = 0; s < 4; ++s) A[v][s] = *(const bf16x8*)(ap + s * 32);
  }

  float wl[4][4];
#pragma unroll
  for (int v = 0; v < 4; ++v)
#pragma unroll
    for (int j = 0; j < 4; ++j) wl[v][j] = 0.f;

  int ut0 = (uc == 0) ? 0 : uc * 12 + 1;       // u-tile split 13/12/12/12
  int cnt = (uc == 0) ? 13 : 12;
  const unsigned short* qb = q_t + (size_t)b * U_CNT * DKH;
  f32x4 zero = {0.f, 0.f, 0.f, 0.f};

  for (int it = 0; it < cnt; ++it) {
    const unsigned short* qp =
        qb + (size_t)((ut0 + it) * 16 + col) * DKH + rowg * 8;
    bf16x8 B0 = *(const bf16x8*)(qp);
    bf16x8 B1 = *(const bf16x8*)(qp + 32);
    bf16x8 B2 = *(const bf16x8*)(qp + 64);
    bf16x8 B3 = *(const bf16x8*)(qp + 96);
    f32x4 acc[4];
#pragma unroll
    for (int v = 0; v < 4; ++v) acc[v] = zero;
#pragma unroll
    for (int v = 0; v < 4; ++v)
      acc[v] = __builtin_amdgcn_mfma_f32_16x16x32_bf16(A[v][0], B0, acc[v], 0, 0, 0);
#pragma unroll
    for (int v = 0; v < 4; ++v)
      acc[v] = __builtin_amdgcn_mfma_f32_16x16x32_bf16(A[v][1], B1, acc[v], 0, 0, 0);
#pragma unroll
    for (int v = 0; v < 4; ++v)
      acc[v] = __builtin_amdgcn_mfma_f32_16x16x32_bf16(A[v][2], B2, acc[v], 0, 0, 0);
#pragma unroll
    for (int v = 0; v < 4; ++v)
      acc[v] = __builtin_amdgcn_mfma_f32_16x16x32_bf16(A[v][3], B3, acc[v], 0, 0, 0);
    // softmax over class (lane's 4 regs + 2 cross-rowg shfl); scores ~N(0,1)
#pragma unroll
    for (int v = 0; v < 4; ++v) {
      float e0 = __expf(acc[v][0]), e1 = __expf(acc[v][1]);
      float e2 = __expf(acc[v][2]), e3 = __expf(acc[v][3]);
      float ps = (e0 + e1) + (e2 + e3);
      ps += __shfl_xor(ps, 16, 64);
      ps += __shfl_xor(ps, 32, 64);
      float r = __builtin_amdgcn_rcpf(ps);
      wl[v][0] += e0 * r; wl[v][1] += e1 * r;
      wl[v][2] += e2 * r; wl[v][3] += e3 * r;
    }
  }
  // sum over u (= cols) via butterfly
#pragma unroll
  for (int v = 0; v < 4; ++v)
#pragma unroll
    for (int j = 0; j < 4; ++j) {
      float x = wl[v][j];
      x += __shfl_xor(x, 1, 64); x += __shfl_xor(x, 2, 64);
      x += __shfl_xor(x, 4, 64); x += __shfl_xor(x, 8, 64);
      wl[v][j] = x;
    }
  __shared__ float wst[4][4][16];   // [wave][v_local][class]
#pragma unroll
  for (int v = 0; v < 4; ++v)
    if (col == v) {
#pragma unroll
      for (int j = 0; j < 4; ++j) wst[wv][v][rowg * 4 + j] = wl[v][j];
    }
  __syncthreads();
  int t = threadIdx.x;
  int vl = t >> 4, c = t & 15;
  w_part[(((size_t)uc * 8 + b) * U_CNT + vb * 16 + vl) * NS + c] =
      wst[vl >> 2][vl & 3][c];
}

// --------------------------- K4: a = sum_n w*sv, reduced on the fly (T1, T2)
// b-inner so sv_t is read exactly once total.
__global__ __launch_bounds__(256)
void align_kernel(const float* __restrict__ w_part, const float* __restrict__ sv_t,
                  float* __restrict__ T1, float* __restrict__ T2) {
  int vt4 = blockIdx.x;   // 196 blocks, 4 v each
  int t = threadIdx.x;
  __shared__ float w_sh[8][4][16];   // [b][v_local][class]
  for (int e = t; e < 512; e += 256) {
    int b = e >> 6, vl = (e >> 4) & 3, n = e & 15;
    float s = 0.f;
#pragma unroll
    for (int uc = 0; uc < 4; ++uc)
      s += w_part[(((size_t)uc * 8 + b) * U_CNT + vt4 * 4 + vl) * NS + n];
    w_sh[b][vl][n] = s;
  }
  __syncthreads();
  int k = t & 127, vh = t >> 7;
  float t1[8], t2[8];
#pragma unroll
  for (int b = 0; b < 8; ++b) { t1[b] = 0.f; t2[b] = 0.f; }
  for (int vi = vh; vi < 4; vi += 2) {
    int v = vt4 * 4 + vi;
    float a[8];
#pragma unroll
    for (int b = 0; b < 8; ++b) a[b] = 0.f;
#pragma unroll
    for (int n = 0; n < NS; ++n) {
      float s = sv_t[((size_t)n * U_CNT + v) * DKH + k];
#pragma unroll
      for (int b = 0; b < 8; ++b) a[b] += w_sh[b][vi][n] * s;
    }
#pragma unroll
    for (int b = 0; b < 8; ++b) { t1[b] += a[b] * a[b]; t2[b] += a[b]; }
  }
  __shared__ float red[8][256];
#pragma unroll
  for (int b = 0; b < 8; ++b) red[b][t] = t2[b];
  __syncthreads();
  if (t < 128) {
#pragma unroll
    for (int b = 0; b < 8; ++b)
      atomicAdd(&T2[b * DKH + t], red[b][t] + red[b][t + 128]);
  }
#pragma unroll
  for (int b = 0; b < 8; ++b) {
    float x = t1[b];
#pragma unroll
    for (int o = 32; o >= 1; o >>= 1) x += __shfl_xor(x, o, 64);
    if ((t & 63) == 0) atomicAdd(&T1[b], x);
  }
}

// ----------------------------------------------------------------- K5: final
__global__ void final_kernel(const float* __restrict__ S1, const float* __restrict__ S2,
                             const float* __restrict__ T1, const float* __restrict__ T2,
                             float* __restrict__ out) {
  int b = blockIdx.x, t = threadIdx.x;  // 128 threads
  float p = S2[b * DKH + t] * T2[b * DKH + t];
#pragma unroll
  for (int o = 32; o >= 1; o >>= 1) p += __shfl_xor(p, o, 64);
  __shared__ float s2[2];
  if ((t & 63) == 0) s2[t >> 6] = p;
  __syncthreads();
  if (t == 0) {
    float cross = s2[0] + s2[1];
    out[b] = (784.0f * (T1[b] + S1[b]) - 2.0f * cross) * (1.0f / (784.0f * 784.0f));
  }
}

// ----------------------------------------------------------------- launcher
extern "C" void kernel_launch(void* const* d_in, const int* in_sizes, int n_in,
                              void* d_out, int out_size, void* d_ws, size_t ws_size,
                              hipStream_t stream) {
  const float* query   = (const float*)d_in[0];
  const float* support = (const float*)d_in[1];
  const float* Wk      = (const float*)d_in[2];
  const float* Wv      = (const float*)d_in[3];
  float* out = (float*)d_out;
  char* ws = (char*)d_ws;

  // workspace layout (256B-aligned)
  unsigned short* Wkv  = (unsigned short*)(ws + 0);          //  256KB
  unsigned short* q_t  = (unsigned short*)(ws + 262144);     //  1.53MB bf16 [8][784][128]
  unsigned short* sk_t = (unsigned short*)(ws + 1867776);    //  3.06MB bf16 [16][784][128]
  float*          sv_t = (float*)(ws + 5079040);             //  6.13MB f32  [16][784][128]
  float*          w_part = (float*)(ws + 11501568);          //  1.53MB f32  [4][8][784][16]
  float*          S1 = (float*)(ws + 13107200);              // 8
  float*          T1 = (float*)(ws + 13107200 + 32);         // 8
  float*          S2 = (float*)(ws + 13107200 + 64);         // 8x128
  float*          T2 = (float*)(ws + 13107200 + 64 + 4096);  // 8x128
  if (ws_size < (size_t)13120000) return;

  hipMemsetAsync(ws + 13107200, 0, 64 + 8192, stream);
  cast_w<<<64, 256, 0, stream>>>(Wk, Wv, Wkv);
  proj_kernel<<<dim3(13, 24), 256, 0, stream>>>(query, support, Wkv, q_t, sk_t, sv_t, S1, S2);
  score_kernel<<<1568, 256, 0, stream>>>(q_t, sk_t, w_part);
  align_kernel<<<196, 256, 0, stream>>>(w_part, sv_t, T1, T2);
  final_kernel<<<8, 128, 0, stream>>>(S1, S2, T1, T2, out);
}

// Round 3
// 239.216 us; speedup vs baseline: 1.3594x; 1.2121x over previous
//
#include <hip/hip_runtime.h>

// Problem constants
#define U_CNT 784   // H*W = 28*28 (both u and v extents)
#define DKH   128   // key/value head dim
#define DD    512   // input channel dim
#define NS    16    // support classes

typedef short bf16x8 __attribute__((ext_vector_type(8)));
typedef float f32x4  __attribute__((ext_vector_type(4)));

__device__ __forceinline__ unsigned short f2bf(float f) {
  unsigned u = __builtin_bit_cast(unsigned, f);
  u += 0x7fffu + ((u >> 16) & 1u);   // round-to-nearest-even
  return (unsigned short)(u >> 16);
}

// ---------------------------------------------------------------- K0: cast W
__global__ void cast_w(const float* __restrict__ Wk, const float* __restrict__ Wv,
                       unsigned short* __restrict__ Wkv) {
  int base = (blockIdx.x * 256 + threadIdx.x) * 8;
#pragma unroll
  for (int i = 0; i < 8; ++i) {
    int e = base + i;
    int ko = e >> 9, d = e & 511;
    float v = (ko < 128) ? Wk[ko * 512 + d] : Wv[(ko - 128) * 512 + d];
    Wkv[e] = f2bf(v);
  }
}

// ------------------------------------------------------------- K1: projection
// Per image m: Y = Wkv @ X (256 x 784), K=512.
//  m<8  (query):  rows 0..127 -> q_t[b][u][k] bf16 (x 1/sqrt(128));
//                 rows 128..255 (qv) -> per-WAVE partials S1p/S2p (plain stores,
//                 NO atomics — atomic same-line RMW contention was the R2 killer).
//  m>=8 (support):rows 0..127 -> sk_t[n][v][k] bf16; rows 128..255 -> sv_t f32.
__global__ __launch_bounds__(256, 2)
void proj_kernel(const float* __restrict__ query, const float* __restrict__ support,
                 const unsigned short* __restrict__ Wkv,
                 unsigned short* __restrict__ q_t, unsigned short* __restrict__ sk_t,
                 float* __restrict__ sv_t, float* __restrict__ S1p, float* __restrict__ S2p) {
  int m = blockIdx.y;
  int wave = threadIdx.x >> 6;
  int p0 = blockIdx.x * 64 + wave * 16;
  if (p0 >= U_CNT) return;                 // ragged last tile (wave-uniform; no barriers in kernel)
  int l = threadIdx.x & 63;
  int col = l & 15, rowg = l >> 4;
  int p = p0 + col;
  const float* X = (m < 8) ? (query + (size_t)m * DD * U_CNT)
                           : (support + (size_t)(m - 8) * DD * U_CNT);
  f32x4 acc[16];
  f32x4 zero = {0.f, 0.f, 0.f, 0.f};
#pragma unroll
  for (int r = 0; r < 16; ++r) acc[r] = zero;

  for (int ds = 0; ds < 16; ++ds) {
    int d0 = ds * 32 + rowg * 8;
    bf16x8 bfrag;
#pragma unroll
    for (int j = 0; j < 8; ++j) {
      float x = X[(size_t)(d0 + j) * U_CNT + p];
      bfrag[j] = (short)f2bf(x);
    }
#pragma unroll
    for (int r = 0; r < 16; ++r) {
      const bf16x8* ap = (const bf16x8*)(Wkv + (size_t)(r * 16 + col) * DD + d0);
      acc[r] = __builtin_amdgcn_mfma_f32_16x16x32_bf16(*ap, bfrag, acc[r], 0, 0, 0);
    }
  }

  if (m < 8) {
    // rows 0..7 -> q_t (scaled bf16)
#pragma unroll
    for (int r = 0; r < 8; ++r) {
      int kb = r * 16 + rowg * 4;
      const float sc = 0.08838834764831845f;  // 1/sqrt(128)
      ushort4 o;
      o.x = f2bf(acc[r][0] * sc); o.y = f2bf(acc[r][1] * sc);
      o.z = f2bf(acc[r][2] * sc); o.w = f2bf(acc[r][3] * sc);
      *(ushort4*)(q_t + (size_t)(m * U_CNT + p) * DKH + kb) = o;
    }
    // rows 8..15 (qv): per-wave partial reductions, plain stores
    int widx = blockIdx.x * 4 + wave;   // valid widx = 0..48 (bx=12 has only wave 0)
    float s1 = 0.f;
#pragma unroll
    for (int r = 8; r < 16; ++r) {
#pragma unroll
      for (int j = 0; j < 4; ++j) {
        float x = acc[r][j];
        s1 += x * x;
        x += __shfl_xor(x, 1, 64); x += __shfl_xor(x, 2, 64);
        x += __shfl_xor(x, 4, 64); x += __shfl_xor(x, 8, 64);
        if (col == 0)
          S2p[((size_t)widx * 8 + m) * DKH + (r - 8) * 16 + rowg * 4 + j] = x;
      }
    }
#pragma unroll
    for (int o = 32; o >= 1; o >>= 1) s1 += __shfl_xor(s1, o, 64);
    if (l == 0) S1p[widx * 8 + m] = s1;
  } else {
    int img = m - 8;
#pragma unroll
    for (int r = 0; r < 16; ++r) {
      int kb = r * 16 + rowg * 4;
      if (r < 8) {
        ushort4 o;
        o.x = f2bf(acc[r][0]); o.y = f2bf(acc[r][1]);
        o.z = f2bf(acc[r][2]); o.w = f2bf(acc[r][3]);
        *(ushort4*)(sk_t + (size_t)(img * U_CNT + p) * DKH + kb) = o;
      } else {
        float4 o = make_float4(acc[r][0], acc[r][1], acc[r][2], acc[r][3]);
        *(float4*)(sv_t + (size_t)(img * U_CNT + p) * DKH + (kb - 128)) = o;
      }
    }
  }
}

// -------------------------------------------- K3: scores + softmax_n + sum_u
// MFMA m-dim = class (16 = all of NS), n-dim = u. Per wave: 4 v's (sk frags
// register-resident), stream q u-tiles. Writes w_part[uc][b][v][n] contiguous.
__global__ __launch_bounds__(256, 3)
void score_kernel(const unsigned short* __restrict__ q_t,
                  const unsigned short* __restrict__ sk_t,
                  float* __restrict__ w_part) {
  int bx = blockIdx.x;            // 1568 = 49 vb * 4 uc * 8 b
  int vb = bx % 49;
  int uc = (bx / 49) & 3;
  int b  = bx / 196;
  int wv = threadIdx.x >> 6;
  int l  = threadIdx.x & 63;
  int col = l & 15, rowg = l >> 4;
  int vbase = vb * 16 + wv * 4;

  bf16x8 A[4][4];
#pragma unroll
  for (int v = 0; v < 4; ++v) {
    const unsigned short* ap =
        sk_t + ((size_t)col * U_CNT + vbase + v) * DKH + rowg * 8;
#pragma unroll
    for (int s = 0; s < 4; ++s) A[v][s] = *(const bf16x8*)(ap + s * 32);
  }

  float wl[4][4];
#pragma unroll
  for (int v = 0; v < 4; ++v)
#pragma unroll
    for (int j = 0; j < 4; ++j) wl[v][j] = 0.f;

  int ut0 = (uc == 0) ? 0 : uc * 12 + 1;       // u-tile split 13/12/12/12
  int cnt = (uc == 0) ? 13 : 12;
  const unsigned short* qb = q_t + (size_t)b * U_CNT * DKH;
  f32x4 zero = {0.f, 0.f, 0.f, 0.f};

  for (int it = 0; it < cnt; ++it) {
    const unsigned short* qp =
        qb + (size_t)((ut0 + it) * 16 + col) * DKH + rowg * 8;
    bf16x8 B0 = *(const bf16x8*)(qp);
    bf16x8 B1 = *(const bf16x8*)(qp + 32);
    bf16x8 B2 = *(const bf16x8*)(qp + 64);
    bf16x8 B3 = *(const bf16x8*)(qp + 96);
    f32x4 acc[4];
#pragma unroll
    for (int v = 0; v < 4; ++v) acc[v] = zero;
#pragma unroll
    for (int v = 0; v < 4; ++v)
      acc[v] = __builtin_amdgcn_mfma_f32_16x16x32_bf16(A[v][0], B0, acc[v], 0, 0, 0);
#pragma unroll
    for (int v = 0; v < 4; ++v)
      acc[v] = __builtin_amdgcn_mfma_f32_16x16x32_bf16(A[v][1], B1, acc[v], 0, 0, 0);
#pragma unroll
    for (int v = 0; v < 4; ++v)
      acc[v] = __builtin_amdgcn_mfma_f32_16x16x32_bf16(A[v][2], B2, acc[v], 0, 0, 0);
#pragma unroll
    for (int v = 0; v < 4; ++v)
      acc[v] = __builtin_amdgcn_mfma_f32_16x16x32_bf16(A[v][3], B3, acc[v], 0, 0, 0);
#pragma unroll
    for (int v = 0; v < 4; ++v) {
      float e0 = __expf(acc[v][0]), e1 = __expf(acc[v][1]);
      float e2 = __expf(acc[v][2]), e3 = __expf(acc[v][3]);
      float ps = (e0 + e1) + (e2 + e3);
      ps += __shfl_xor(ps, 16, 64);
      ps += __shfl_xor(ps, 32, 64);
      float r = __builtin_amdgcn_rcpf(ps);
      wl[v][0] += e0 * r; wl[v][1] += e1 * r;
      wl[v][2] += e2 * r; wl[v][3] += e3 * r;
    }
  }
#pragma unroll
  for (int v = 0; v < 4; ++v)
#pragma unroll
    for (int j = 0; j < 4; ++j) {
      float x = wl[v][j];
      x += __shfl_xor(x, 1, 64); x += __shfl_xor(x, 2, 64);
      x += __shfl_xor(x, 4, 64); x += __shfl_xor(x, 8, 64);
      wl[v][j] = x;
    }
  __shared__ float wst[4][4][16];   // [wave][v_local][class]
#pragma unroll
  for (int v = 0; v < 4; ++v)
    if (col == v) {
#pragma unroll
      for (int j = 0; j < 4; ++j) wst[wv][v][rowg * 4 + j] = wl[v][j];
    }
  __syncthreads();
  int t = threadIdx.x;
  int vl = t >> 4, c = t & 15;
  w_part[(((size_t)uc * 8 + b) * U_CNT + vb * 16 + vl) * NS + c] =
      wst[vl >> 2][vl & 3][c];
}

// --------------------------- K4: a = sum_n w*sv -> per-block partials (T1p,T2p)
// b-inner so sv_t is read exactly once. NO global atomics.
__global__ __launch_bounds__(256)
void align_kernel(const float* __restrict__ w_part, const float* __restrict__ sv_t,
                  float* __restrict__ T1p, float* __restrict__ T2p) {
  int vt4 = blockIdx.x;   // 196 blocks, 4 v each
  int t = threadIdx.x;
  __shared__ float w_sh[8][4][16];   // [b][v_local][class]
  for (int e = t; e < 512; e += 256) {
    int b = e >> 6, vl = (e >> 4) & 3, n = e & 15;
    float s = 0.f;
#pragma unroll
    for (int uc = 0; uc < 4; ++uc)
      s += w_part[(((size_t)uc * 8 + b) * U_CNT + vt4 * 4 + vl) * NS + n];
    w_sh[b][vl][n] = s;
  }
  __syncthreads();
  int k = t & 127, vh = t >> 7;
  float t1[8], t2[8];
#pragma unroll
  for (int b = 0; b < 8; ++b) { t1[b] = 0.f; t2[b] = 0.f; }
  for (int vi = vh; vi < 4; vi += 2) {
    int v = vt4 * 4 + vi;
    float a[8];
#pragma unroll
    for (int b = 0; b < 8; ++b) a[b] = 0.f;
#pragma unroll
    for (int n = 0; n < NS; ++n) {
      float s = sv_t[((size_t)n * U_CNT + v) * DKH + k];
#pragma unroll
      for (int b = 0; b < 8; ++b) a[b] += w_sh[b][vi][n] * s;
    }
#pragma unroll
    for (int b = 0; b < 8; ++b) { t1[b] += a[b] * a[b]; t2[b] += a[b]; }
  }
  // combine the two vh-halves through LDS, then plain coalesced stores
  __shared__ float red[8][128];
  if (t >= 128) {
#pragma unroll
    for (int b = 0; b < 8; ++b) red[b][k] = t2[b];
  }
  __syncthreads();
  if (t < 128) {
#pragma unroll
    for (int b = 0; b < 8; ++b)
      T2p[((size_t)vt4 * 8 + b) * DKH + k] = t2[b] + red[b][k];
  }
  __shared__ float sw1[4][8];
#pragma unroll
  for (int b = 0; b < 8; ++b) {
    float x = t1[b];
#pragma unroll
    for (int o = 32; o >= 1; o >>= 1) x += __shfl_xor(x, o, 64);
    if ((t & 63) == 0) sw1[t >> 6][b] = x;
  }
  __syncthreads();
  if (t < 8) T1p[vt4 * 8 + t] = sw1[0][t] + sw1[1][t] + sw1[2][t] + sw1[3][t];
}

// ------------------------------------------- K5: reduce partials + closed form
// out[b] = (784*(T1+S1) - 2*sum_k S2[k]*T2[k]) / 784^2
__global__ __launch_bounds__(256)
void final_kernel(const float* __restrict__ S1p, const float* __restrict__ S2p,
                  const float* __restrict__ T1p, const float* __restrict__ T2p,
                  float* __restrict__ out) {
  int b = blockIdx.x, t = threadIdx.x;
  int k = t & 127, h = t >> 7;
  float s2s = 0.f, t2s = 0.f;
  for (int w = h; w < 49; w += 2)     s2s += S2p[((size_t)w * 8 + b) * DKH + k];
  for (int nb = h; nb < 196; nb += 2) t2s += T2p[((size_t)nb * 8 + b) * DKH + k];
  float sc = 0.f;  // S1 and T1 contributions summed together
  for (int i = t; i < 49; i += 256)  sc += S1p[i * 8 + b];
  for (int i = t; i < 196; i += 256) sc += T1p[i * 8 + b];
  __shared__ float c2[2][128];
  if (h == 1) { c2[0][k] = s2s; c2[1][k] = t2s; }
  __syncthreads();
  float p = 0.f;
  if (h == 0) p = (s2s + c2[0][k]) * (t2s + c2[1][k]);
  float val = 784.0f * sc - 2.0f * p;
#pragma unroll
  for (int o = 32; o >= 1; o >>= 1) val += __shfl_xor(val, o, 64);
  __shared__ float sw[4];
  if ((t & 63) == 0) sw[t >> 6] = val;
  __syncthreads();
  if (t == 0)
    out[b] = (sw[0] + sw[1] + sw[2] + sw[3]) * (1.0f / (784.0f * 784.0f));
}

// ----------------------------------------------------------------- launcher
extern "C" void kernel_launch(void* const* d_in, const int* in_sizes, int n_in,
                              void* d_out, int out_size, void* d_ws, size_t ws_size,
                              hipStream_t stream) {
  const float* query   = (const float*)d_in[0];
  const float* support = (const float*)d_in[1];
  const float* Wk      = (const float*)d_in[2];
  const float* Wv      = (const float*)d_in[3];
  float* out = (float*)d_out;
  char* ws = (char*)d_ws;

  // workspace layout (256B-aligned)
  unsigned short* Wkv  = (unsigned short*)(ws + 0);          //  256KB
  unsigned short* q_t  = (unsigned short*)(ws + 262144);     //  1.53MB bf16 [8][784][128]
  unsigned short* sk_t = (unsigned short*)(ws + 1867776);    //  3.06MB bf16 [16][784][128]
  float*          sv_t = (float*)(ws + 5079040);             //  6.13MB f32  [16][784][128]
  float*          w_part = (float*)(ws + 11501568);          //  1.53MB f32  [4][8][784][16]
  float*          S1p  = (float*)(ws + 13107200);            //  49x8   (2KB reserved)
  float*          T1p  = (float*)(ws + 13109248);            //  196x8  (8KB reserved)
  float*          S2p  = (float*)(ws + 13117440);            //  49x8x128  (196KB)
  float*          T2p  = (float*)(ws + 13318144);            //  196x8x128 (784KB) -> ends 14120960
  if (ws_size < (size_t)14121000) return;

  cast_w<<<64, 256, 0, stream>>>(Wk, Wv, Wkv);
  proj_kernel<<<dim3(13, 24), 256, 0, stream>>>(query, support, Wkv, q_t, sk_t, sv_t, S1p, S2p);
  score_kernel<<<1568, 256, 0, stream>>>(q_t, sk_t, w_part);
  align_kernel<<<196, 256, 0, stream>>>(w_part, sv_t, T1p, T2p);
  final_kernel<<<8, 256, 0, stream>>>(S1p, S2p, T1p, T2p, out);
}

// Round 4
// 192.626 us; speedup vs baseline: 1.6882x; 1.2419x over previous
//
#include <hip/hip_runtime.h>

// Problem constants
#define U_CNT 784   // H*W = 28*28 (both u and v extents)
#define DKH   128   // key/value head dim
#define DD    512   // input channel dim
#define NS    16    // support classes

typedef short bf16x8 __attribute__((ext_vector_type(8)));
typedef float f32x4  __attribute__((ext_vector_type(4)));

__device__ __forceinline__ unsigned short f2bf(float f) {
  unsigned u = __builtin_bit_cast(unsigned, f);
  u += 0x7fffu + ((u >> 16) & 1u);   // round-to-nearest-even
  return (unsigned short)(u >> 16);
}

// ---------------------------------------------------------------- K0: cast W
__global__ void cast_w(const float* __restrict__ Wk, const float* __restrict__ Wv,
                       unsigned short* __restrict__ Wkv) {
  int base = (blockIdx.x * 256 + threadIdx.x) * 8;
#pragma unroll
  for (int i = 0; i < 8; ++i) {
    int e = base + i;
    int ko = e >> 9, d = e & 511;
    float v = (ko < 128) ? Wk[ko * 512 + d] : Wv[(ko - 128) * 512 + d];
    Wkv[e] = f2bf(v);
  }
}

// ------------------------------------------------------------- K1: projection
// Grid (49 p-tiles, 24 images), 4 waves/block. Each wave computes 4 of the 16
// output-row groups (r = wave*4+rr) so per-wave latency chain is 4x shorter and
// grid is 4x larger than R3 (312->1176 blocks). All 4 waves load identical X
// fragments -> L1 broadcast. No atomics anywhere.
__global__ __launch_bounds__(256)
void proj_kernel(const float* __restrict__ query, const float* __restrict__ support,
                 const unsigned short* __restrict__ Wkv,
                 unsigned short* __restrict__ q_t, unsigned short* __restrict__ sk_t,
                 float* __restrict__ sv_t, float* __restrict__ S1p, float* __restrict__ S2p) {
  int pt = blockIdx.x;        // 0..48
  int m  = blockIdx.y;        // 0..23
  int wave = threadIdx.x >> 6;
  int l = threadIdx.x & 63;
  int col = l & 15, rowg = l >> 4;
  int p = pt * 16 + col;
  const float* X = (m < 8) ? (query + (size_t)m * DD * U_CNT)
                           : (support + (size_t)(m - 8) * DD * U_CNT);
  f32x4 acc[4];
  f32x4 zero = {0.f, 0.f, 0.f, 0.f};
#pragma unroll
  for (int rr = 0; rr < 4; ++rr) acc[rr] = zero;

  for (int ds = 0; ds < 16; ++ds) {
    int d0 = ds * 32 + rowg * 8;
    bf16x8 bfrag;
#pragma unroll
    for (int j = 0; j < 8; ++j) {
      float x = X[(size_t)(d0 + j) * U_CNT + p];
      bfrag[j] = (short)f2bf(x);
    }
#pragma unroll
    for (int rr = 0; rr < 4; ++rr) {
      int r = wave * 4 + rr;
      const bf16x8* ap = (const bf16x8*)(Wkv + (size_t)(r * 16 + col) * DD + d0);
      acc[rr] = __builtin_amdgcn_mfma_f32_16x16x32_bf16(*ap, bfrag, acc[rr], 0, 0, 0);
    }
  }

  if (m < 8) {
    if (wave < 2) {
      // rows 0..127 -> q_t (scaled bf16)
#pragma unroll
      for (int rr = 0; rr < 4; ++rr) {
        int r = wave * 4 + rr;
        int kb = r * 16 + rowg * 4;
        const float sc = 0.08838834764831845f;  // 1/sqrt(128)
        ushort4 o;
        o.x = f2bf(acc[rr][0] * sc); o.y = f2bf(acc[rr][1] * sc);
        o.z = f2bf(acc[rr][2] * sc); o.w = f2bf(acc[rr][3] * sc);
        *(ushort4*)(q_t + (size_t)(m * U_CNT + p) * DKH + kb) = o;
      }
    } else {
      // rows 128..255 (qv): per-wave partials, plain stores. wave2 -> k 0..63,
      // wave3 -> k 64..127 of S2p[pt][m][.]; S1p[ (wave-2)*49+pt ][m].
      float s1 = 0.f;
#pragma unroll
      for (int rr = 0; rr < 4; ++rr) {
        int r = wave * 4 + rr;          // 8..15
#pragma unroll
        for (int j = 0; j < 4; ++j) {
          float x = acc[rr][j];
          s1 += x * x;
          x += __shfl_xor(x, 1, 64); x += __shfl_xor(x, 2, 64);
          x += __shfl_xor(x, 4, 64); x += __shfl_xor(x, 8, 64);
          if (col == 0)
            S2p[((size_t)pt * 8 + m) * DKH + (r - 8) * 16 + rowg * 4 + j] = x;
        }
      }
#pragma unroll
      for (int o = 32; o >= 1; o >>= 1) s1 += __shfl_xor(s1, o, 64);
      if (l == 0) S1p[((wave - 2) * 49 + pt) * 8 + m] = s1;
    }
  } else {
    int img = m - 8;
    if (wave < 2) {
#pragma unroll
      for (int rr = 0; rr < 4; ++rr) {
        int r = wave * 4 + rr;
        int kb = r * 16 + rowg * 4;
        ushort4 o;
        o.x = f2bf(acc[rr][0]); o.y = f2bf(acc[rr][1]);
        o.z = f2bf(acc[rr][2]); o.w = f2bf(acc[rr][3]);
        *(ushort4*)(sk_t + (size_t)(img * U_CNT + p) * DKH + kb) = o;
      }
    } else {
#pragma unroll
      for (int rr = 0; rr < 4; ++rr) {
        int r = wave * 4 + rr;
        int kb = (r - 8) * 16 + rowg * 4;
        float4 o = make_float4(acc[rr][0], acc[rr][1], acc[rr][2], acc[rr][3]);
        *(float4*)(sv_t + (size_t)(img * U_CNT + p) * DKH + kb) = o;
      }
    }
  }
}

// -------------------------------------------- K3: scores + softmax_n + sum_u
// MFMA m-dim = class (16 = all of NS), n-dim = u. Per wave: 4 v's (sk frags
// register-resident), stream q u-tiles. Writes w_part[uc][b][v][n] contiguous.
__global__ __launch_bounds__(256, 3)
void score_kernel(const unsigned short* __restrict__ q_t,
                  const unsigned short* __restrict__ sk_t,
                  float* __restrict__ w_part) {
  int bx = blockIdx.x;            // 1568 = 49 vb * 4 uc * 8 b
  int vb = bx % 49;
  int uc = (bx / 49) & 3;
  int b  = bx / 196;
  int wv = threadIdx.x >> 6;
  int l  = threadIdx.x & 63;
  int col = l & 15, rowg = l >> 4;
  int vbase = vb * 16 + wv * 4;

  bf16x8 A[4][4];
#pragma unroll
  for (int v = 0; v < 4; ++v) {
    const unsigned short* ap =
        sk_t + ((size_t)col * U_CNT + vbase + v) * DKH + rowg * 8;
#pragma unroll
    for (int s = 0; s < 4; ++s) A[v][s] = *(const bf16x8*)(ap + s * 32);
  }

  float wl[4][4];
#pragma unroll
  for (int v = 0; v < 4; ++v)
#pragma unroll
    for (int j = 0; j < 4; ++j) wl[v][j] = 0.f;

  int ut0 = (uc == 0) ? 0 : uc * 12 + 1;       // u-tile split 13/12/12/12
  int cnt = (uc == 0) ? 13 : 12;
  const unsigned short* qb = q_t + (size_t)b * U_CNT * DKH;
  f32x4 zero = {0.f, 0.f, 0.f, 0.f};

  for (int it = 0; it < cnt; ++it) {
    const unsigned short* qp =
        qb + (size_t)((ut0 + it) * 16 + col) * DKH + rowg * 8;
    bf16x8 B0 = *(const bf16x8*)(qp);
    bf16x8 B1 = *(const bf16x8*)(qp + 32);
    bf16x8 B2 = *(const bf16x8*)(qp + 64);
    bf16x8 B3 = *(const bf16x8*)(qp + 96);
    f32x4 acc[4];
#pragma unroll
    for (int v = 0; v < 4; ++v) acc[v] = zero;
#pragma unroll
    for (int v = 0; v < 4; ++v)
      acc[v] = __builtin_amdgcn_mfma_f32_16x16x32_bf16(A[v][0], B0, acc[v], 0, 0, 0);
#pragma unroll
    for (int v = 0; v < 4; ++v)
      acc[v] = __builtin_amdgcn_mfma_f32_16x16x32_bf16(A[v][1], B1, acc[v], 0, 0, 0);
#pragma unroll
    for (int v = 0; v < 4; ++v)
      acc[v] = __builtin_amdgcn_mfma_f32_16x16x32_bf16(A[v][2], B2, acc[v], 0, 0, 0);
#pragma unroll
    for (int v = 0; v < 4; ++v)
      acc[v] = __builtin_amdgcn_mfma_f32_16x16x32_bf16(A[v][3], B3, acc[v], 0, 0, 0);
#pragma unroll
    for (int v = 0; v < 4; ++v) {
      float e0 = __expf(acc[v][0]), e1 = __expf(acc[v][1]);
      float e2 = __expf(acc[v][2]), e3 = __expf(acc[v][3]);
      float ps = (e0 + e1) + (e2 + e3);
      ps += __shfl_xor(ps, 16, 64);
      ps += __shfl_xor(ps, 32, 64);
      float r = __builtin_amdgcn_rcpf(ps);
      wl[v][0] += e0 * r; wl[v][1] += e1 * r;
      wl[v][2] += e2 * r; wl[v][3] += e3 * r;
    }
  }
#pragma unroll
  for (int v = 0; v < 4; ++v)
#pragma unroll
    for (int j = 0; j < 4; ++j) {
      float x = wl[v][j];
      x += __shfl_xor(x, 1, 64); x += __shfl_xor(x, 2, 64);
      x += __shfl_xor(x, 4, 64); x += __shfl_xor(x, 8, 64);
      wl[v][j] = x;
    }
  __shared__ float wst[4][4][16];   // [wave][v_local][class]
#pragma unroll
  for (int v = 0; v < 4; ++v)
    if (col == v) {
#pragma unroll
      for (int j = 0; j < 4; ++j) wst[wv][v][rowg * 4 + j] = wl[v][j];
    }
  __syncthreads();
  int t = threadIdx.x;
  int vl = t >> 4, c = t & 15;
  w_part[(((size_t)uc * 8 + b) * U_CNT + vb * 16 + vl) * NS + c] =
      wst[vl >> 2][vl & 3][c];
}

// --------------------------- K4: a = sum_n w*sv -> per-block partials (T1p,T2p)
__global__ __launch_bounds__(256)
void align_kernel(const float* __restrict__ w_part, const float* __restrict__ sv_t,
                  float* __restrict__ T1p, float* __restrict__ T2p) {
  int vt4 = blockIdx.x;   // 196 blocks, 4 v each
  int t = threadIdx.x;
  __shared__ float w_sh[8][4][16];   // [b][v_local][class]
  for (int e = t; e < 512; e += 256) {
    int b = e >> 6, vl = (e >> 4) & 3, n = e & 15;
    float s = 0.f;
#pragma unroll
    for (int uc = 0; uc < 4; ++uc)
      s += w_part[(((size_t)uc * 8 + b) * U_CNT + vt4 * 4 + vl) * NS + n];
    w_sh[b][vl][n] = s;
  }
  __syncthreads();
  int k = t & 127, vh = t >> 7;
  float t1[8], t2[8];
#pragma unroll
  for (int b = 0; b < 8; ++b) { t1[b] = 0.f; t2[b] = 0.f; }
  for (int vi = vh; vi < 4; vi += 2) {
    int v = vt4 * 4 + vi;
    float a[8];
#pragma unroll
    for (int b = 0; b < 8; ++b) a[b] = 0.f;
#pragma unroll
    for (int n = 0; n < NS; ++n) {
      float s = sv_t[((size_t)n * U_CNT + v) * DKH + k];
#pragma unroll
      for (int b = 0; b < 8; ++b) a[b] += w_sh[b][vi][n] * s;
    }
#pragma unroll
    for (int b = 0; b < 8; ++b) { t1[b] += a[b] * a[b]; t2[b] += a[b]; }
  }
  __shared__ float red[8][128];
  if (t >= 128) {
#pragma unroll
    for (int b = 0; b < 8; ++b) red[b][k] = t2[b];
  }
  __syncthreads();
  if (t < 128) {
#pragma unroll
    for (int b = 0; b < 8; ++b)
      T2p[((size_t)vt4 * 8 + b) * DKH + k] = t2[b] + red[b][k];
  }
  __shared__ float sw1[4][8];
#pragma unroll
  for (int b = 0; b < 8; ++b) {
    float x = t1[b];
#pragma unroll
    for (int o = 32; o >= 1; o >>= 1) x += __shfl_xor(x, o, 64);
    if ((t & 63) == 0) sw1[t >> 6][b] = x;
  }
  __syncthreads();
  if (t < 8) T1p[vt4 * 8 + t] = sw1[0][t] + sw1[1][t] + sw1[2][t] + sw1[3][t];
}

// ------------------------------- K5a: parallel partial reduction (40 blocks)
// blocks 0..31: T2[b][k] over 196 vt4-partials (b = bx/4, k-quarter = bx%4)
// blocks 32..39: S2[b][k] over 49 wave-partials + ST1[b] = S1[b]+T1[b]
__global__ __launch_bounds__(256)
void reduce_partials(const float* __restrict__ S1p, const float* __restrict__ T1p,
                     const float* __restrict__ S2p, const float* __restrict__ T2p,
                     float* __restrict__ S2, float* __restrict__ T2,
                     float* __restrict__ ST1) {
  __shared__ float smem[264];
  int bx = blockIdx.x, t = threadIdx.x;
  if (bx < 32) {
    int b = bx >> 2, kq = bx & 3;
    int kl = t & 31, g = t >> 5;           // 8 groups x 32 k-lanes
    int k = kq * 32 + kl;
    float s = 0.f;
    for (int w = g; w < 196; w += 8)
      s += T2p[((size_t)w * 8 + b) * DKH + k];
    smem[g * 32 + kl] = s;
    __syncthreads();
    if (t < 32) {
      float v = 0.f;
#pragma unroll
      for (int g2 = 0; g2 < 8; ++g2) v += smem[g2 * 32 + t];
      T2[b * DKH + kq * 32 + t] = v;
    }
  } else {
    int b = bx - 32;
    int k = t & 127, h = t >> 7;
    float s = 0.f;
    for (int w = h; w < 49; w += 2)
      s += S2p[((size_t)w * 8 + b) * DKH + k];
    if (h == 1) smem[k] = s;
    __syncthreads();
    if (h == 0) S2[b * DKH + k] = s + smem[k];
    float c = 0.f;
    for (int i = t; i < 98; i += 256)  c += S1p[i * 8 + b];
    for (int i = t; i < 196; i += 256) c += T1p[i * 8 + b];
#pragma unroll
    for (int o = 32; o >= 1; o >>= 1) c += __shfl_xor(c, o, 64);
    if ((t & 63) == 0) smem[256 + (t >> 6)] = c;
    __syncthreads();
    if (t == 0) ST1[b] = smem[256] + smem[257] + smem[258] + smem[259];
  }
}

// ----------------------------------------------------------------- K5b: final
__global__ void final_kernel(const float* __restrict__ S2, const float* __restrict__ T2,
                             const float* __restrict__ ST1, float* __restrict__ out) {
  int b = blockIdx.x, t = threadIdx.x;  // 128 threads
  float p = S2[b * DKH + t] * T2[b * DKH + t];
#pragma unroll
  for (int o = 32; o >= 1; o >>= 1) p += __shfl_xor(p, o, 64);
  __shared__ float s2[2];
  if ((t & 63) == 0) s2[t >> 6] = p;
  __syncthreads();
  if (t == 0)
    out[b] = (784.0f * ST1[b] - 2.0f * (s2[0] + s2[1])) * (1.0f / (784.0f * 784.0f));
}

// ----------------------------------------------------------------- launcher
extern "C" void kernel_launch(void* const* d_in, const int* in_sizes, int n_in,
                              void* d_out, int out_size, void* d_ws, size_t ws_size,
                              hipStream_t stream) {
  const float* query   = (const float*)d_in[0];
  const float* support = (const float*)d_in[1];
  const float* Wk      = (const float*)d_in[2];
  const float* Wv      = (const float*)d_in[3];
  float* out = (float*)d_out;
  char* ws = (char*)d_ws;

  // workspace layout (256B-aligned)
  unsigned short* Wkv  = (unsigned short*)(ws + 0);          //  256KB
  unsigned short* q_t  = (unsigned short*)(ws + 262144);     //  bf16 [8][784][128]
  unsigned short* sk_t = (unsigned short*)(ws + 1867776);    //  bf16 [16][784][128]
  float*          sv_t = (float*)(ws + 5079040);             //  f32  [16][784][128]
  float*          w_part = (float*)(ws + 11501568);          //  f32  [4][8][784][16]
  float*          S1p  = (float*)(ws + 13107200);            //  [98][8]      (4KB res)
  float*          T1p  = (float*)(ws + 13111296);            //  [196][8]     (8KB res)
  float*          S2p  = (float*)(ws + 13119488);            //  [49][8][128]  196KB
  float*          T2p  = (float*)(ws + 13320192);            //  [196][8][128] 784KB
  float*          S2   = (float*)(ws + 14123008);            //  [8][128]
  float*          T2   = (float*)(ws + 14127104);            //  [8][128]
  float*          ST1  = (float*)(ws + 14131200);            //  [8]
  if (ws_size < (size_t)14131300) return;

  cast_w<<<64, 256, 0, stream>>>(Wk, Wv, Wkv);
  proj_kernel<<<dim3(49, 24), 256, 0, stream>>>(query, support, Wkv, q_t, sk_t, sv_t, S1p, S2p);
  score_kernel<<<1568, 256, 0, stream>>>(q_t, sk_t, w_part);
  align_kernel<<<196, 256, 0, stream>>>(w_part, sv_t, T1p, T2p);
  reduce_partials<<<40, 256, 0, stream>>>(S1p, T1p, S2p, T2p, S2, T2, ST1);
  final_kernel<<<8, 128, 0, stream>>>(S2, T2, ST1, out);
}